// Round 9
// baseline (311.370 us; speedup 1.0000x reference)
//
#include <hip/hip_runtime.h>

typedef unsigned short u16;
typedef unsigned int u32;

#define NC 50000
#define NN 10000
#define NG 20000
#define NE 100000
#define NSCAN 150016   // 5 dst-count regions (150,000) padded
#define NBLK 74        // ceil(NSCAN / 2048)

// CSR dst regions inside hist/bases (element offsets):
// pins_dst    [0,      10000)   -> net rows    (gc payload)
// connect_dst [10000,  30000)   -> gcell rows  (gc payload)
// pt_dst      [30000,  50000)   -> gcell rows  (gc payload)
// pinned_dst  [50000, 100000)   -> cell rows   (nn payload, pos-300000)
// pf_dst      [100000,150000)   -> cell rows   (nn payload, pos-300000)

// ---------- bf16 helpers (workspace T tables only) ----------
__device__ __forceinline__ float bflo(u32 a) { return __uint_as_float(a << 16); }
__device__ __forceinline__ float bfhi(u32 a) { return __uint_as_float(a & 0xFFFF0000u); }
__device__ __forceinline__ u16 fbf(float f) {
  u32 u = __float_as_uint(f);
  return (u16)((u + 0x7FFFu + ((u >> 16) & 1u)) >> 16);  // RNE
}

// one NNConv edge message for lane-output o
__device__ __forceinline__ float nn_msg(int e, int s, const float* __restrict__ ef,
                                        const u16* __restrict__ T,
                                        const float* __restrict__ C, int o) {
  const float4* efp = reinterpret_cast<const float4*>(ef + (size_t)e * 16);
  float4 ea = efp[0], eb = efp[1], ec = efp[2], ed = efp[3];
  const uint4* tp = reinterpret_cast<const uint4*>(T + (size_t)s * 512 + o * 16);
  uint4 ta = tp[0], tb = tp[1];
  float m = C[(size_t)s * 32 + o];
  m += ea.x * bflo(ta.x) + ea.y * bfhi(ta.x) + ea.z * bflo(ta.y) + ea.w * bfhi(ta.y);
  m += eb.x * bflo(ta.z) + eb.y * bfhi(ta.z) + eb.z * bflo(ta.w) + eb.w * bfhi(ta.w);
  m += ec.x * bflo(tb.x) + ec.y * bfhi(tb.x) + ec.z * bflo(tb.y) + ec.w * bfhi(tb.y);
  m += ed.x * bflo(tb.z) + ed.y * bfhi(tb.z) + ed.z * bflo(tb.w) + ed.w * bfhi(tb.w);
  return m;
}

// ---------- K_FRONT: transform (469) | C (1875) | hist (196) ----------
// transform: 64 nodes/block, thread = (jj 0..127, nodegroup 0..3) computing
//   4 consecutive j for 16 nodes. h via ds_read_b128, w[4][32] in VGPRs.
//   Per b128 read: 16 FMAs -> VALU-bound (was 2 FMA/b32 read -> LDS-bound).
__global__ __launch_bounds__(512) void k_front(
    const float* __restrict__ feat_net, const float* __restrict__ feat_han,
    const float* __restrict__ W_topo, const float* __restrict__ b_topo,
    u16* __restrict__ T_net, u16* __restrict__ T_han,
    float* __restrict__ C_net, float* __restrict__ C_han,
    const int* __restrict__ pins_src, const int* __restrict__ pins_dst,
    const int* __restrict__ pinned_dst, const int* __restrict__ pf_dst,
    const int* __restrict__ connect_src, const int* __restrict__ connect_dst,
    const int* __restrict__ pt_src, const int* __restrict__ pt_dst,
    int* __restrict__ hist, int* __restrict__ srccnt) {
  int b = blockIdx.x;
  int tid = threadIdx.x;
  if (b < 469) {  // ---- transform: nodes [b*64, b*64+64) of 30000 ----
    __shared__ float hs[64][32];  // 8 KB
    int nd0 = b * 64;
    {  // stage: thread t loads float4 at element t*4 of the 64x32 tile
      int idx = tid * 4;
      int nl = idx >> 5, i = idx & 31;
      int ng = min(nd0 + nl, 29999);  // clamp (rows >= 30000 unused)
      const float* rp = (ng < NN) ? feat_net + (size_t)ng * 32
                                  : feat_han + (size_t)(ng - NN) * 32;
      *reinterpret_cast<float4*>(&hs[nl][i]) =
          *reinterpret_cast<const float4*>(rp + i);
    }
    int jj = tid & 127, grp = tid >> 7;  // grp wave-uniform (64 | 128)
    int j0 = jj * 4;
    int o = j0 >> 4, p0 = j0 & 15;  // 4 consecutive j share o (4jj%16 in {0,4,8,12})
    float w0[32], w1[32], w2[32], w3[32];
#pragma unroll
    for (int i = 0; i < 32; i++) {
      w0[i] = W_topo[(p0 + 0) * 1024 + i * 32 + o];
      w1[i] = W_topo[(p0 + 1) * 1024 + i * 32 + o];
      w2[i] = W_topo[(p0 + 2) * 1024 + i * 32 + o];
      w3[i] = W_topo[(p0 + 3) * 1024 + i * 32 + o];
    }
    __syncthreads();
#pragma unroll 2
    for (int n = 0; n < 16; n++) {
      int nl = grp * 16 + n;
      float a0 = 0.f, a1 = 0.f, a2 = 0.f, a3 = 0.f;
#pragma unroll
      for (int i4 = 0; i4 < 32; i4 += 4) {
        float4 h = *reinterpret_cast<float4*>(&hs[nl][i4]);  // b128 broadcast
        a0 += h.x * w0[i4] + h.y * w0[i4 + 1] + h.z * w0[i4 + 2] + h.w * w0[i4 + 3];
        a1 += h.x * w1[i4] + h.y * w1[i4 + 1] + h.z * w1[i4 + 2] + h.w * w1[i4 + 3];
        a2 += h.x * w2[i4] + h.y * w2[i4 + 1] + h.z * w2[i4 + 2] + h.w * w2[i4 + 3];
        a3 += h.x * w3[i4] + h.y * w3[i4 + 1] + h.z * w3[i4 + 2] + h.w * w3[i4 + 3];
      }
      int s = nd0 + nl;
      if (s < 30000) {
        uint2 pk = make_uint2((u32)fbf(a0) | ((u32)fbf(a1) << 16),
                              (u32)fbf(a2) | ((u32)fbf(a3) << 16));
        u16* tb = (s < NN) ? T_net + (size_t)s * 512 + j0
                           : T_han + (size_t)(s - NN) * 512 + j0;
        *reinterpret_cast<uint2*>(tb) = pk;
      }
    }
    return;
  }
  if (b < 2344) {  // ---- C: (NN+NG)*32 = 960,000 = 1875*512 exact ----
    int t = (b - 469) * 512 + tid;
    int s2 = t >> 5, o = t & 31;
    bool han = s2 >= NN;
    const float* feat = han ? feat_han : feat_net;
    float* C = han ? C_han : C_net;
    int s = han ? s2 - NN : s2;
    float acc = 0.f;
#pragma unroll 8
    for (int i = 0; i < 32; i++)
      acc += feat[(size_t)s * 32 + i] * b_topo[i * 32 + o];
    C[(size_t)s * 32 + o] = acc;
    return;
  }
  // ---- hist ----
  int e = (b - 2344) * 512 + tid;
  if (e >= NE) return;
  atomicAdd(&hist[pins_dst[e]], 1);
  atomicAdd(&hist[10000 + connect_dst[e]], 1);
  atomicAdd(&hist[30000 + pt_dst[e]], 1);
  atomicAdd(&hist[50000 + pinned_dst[e]], 1);
  atomicAdd(&hist[100000 + pf_dst[e]], 1);
  atomicAdd(&srccnt[pins_src[e]], 1);            // cell  [0,50000)
  atomicAdd(&srccnt[50000 + connect_src[e]], 1); // gcell [50000,70000)
  atomicAdd(&srccnt[70000 + pt_src[e]], 1);      // cell  [70000,120000)
}

// ---------- K_SCAN: single-dispatch exclusive scan ----------
// Each block recomputes its own carry (sum of all counts before its range).
__global__ __launch_bounds__(256) void k_scan(
    const int* __restrict__ cnt, int* __restrict__ bases) {
  __shared__ int sm[256];
  __shared__ int carryS;
  int b = blockIdx.x, tid = threadIdx.x;
  // carry = sum cnt[0, b*2048)
  int lim = b * 2048;
  int part = 0;
  for (int i = tid * 4; i < lim; i += 1024) {
    int4 v = *reinterpret_cast<const int4*>(cnt + i);
    part += v.x + v.y + v.z + v.w;
  }
  sm[tid] = part;
  __syncthreads();
  for (int off = 128; off > 0; off >>= 1) {
    if (tid < off) sm[tid] += sm[tid + off];
    __syncthreads();
  }
  if (tid == 0) carryS = sm[0];
  __syncthreads();
  // local exclusive scan of this block's 2048 counts
  int base = b * 2048 + tid * 8;
  int v[8];
  int tot = 0;
#pragma unroll
  for (int j = 0; j < 8; j++) {
    int i = base + j;
    v[j] = (i < NSCAN) ? cnt[i] : 0;
    tot += v[j];
  }
  sm[tid] = tot;
  __syncthreads();
  for (int off = 1; off < 256; off <<= 1) {
    int add = (tid >= off) ? sm[tid - off] : 0;
    __syncthreads();
    sm[tid] += add;
    __syncthreads();
  }
  int excl = sm[tid] - tot + carryS;
#pragma unroll
  for (int j = 0; j < 8; j++) {
    int i = base + j;
    if (i < NSCAN) bases[i] = excl;
    excl += v[j];
  }
}

// ---------- K_FILL: payload CSRs ----------
// gc (rel 0..2): csr_gc[pos] = (src, bits(rsqrt(deg_src)))
// nn (rel 3..4): csr_nn[pos-300000] = (e, src)
__global__ __launch_bounds__(512) void k_fill(
    const int* __restrict__ pins_src, const int* __restrict__ pins_dst,
    const int* __restrict__ connect_src, const int* __restrict__ connect_dst,
    const int* __restrict__ pt_src, const int* __restrict__ pt_dst,
    const int* __restrict__ pinned_src, const int* __restrict__ pinned_dst,
    const int* __restrict__ pf_src, const int* __restrict__ pf_dst,
    const int* __restrict__ srccnt,
    const int* __restrict__ bases, int* __restrict__ cursor,
    int2* __restrict__ csr_gc, int2* __restrict__ csr_nn) {
  int t = blockIdx.x * 512 + threadIdx.x;
  if (t >= 5 * NE) return;
  int r = (t >= NE) + (t >= 2 * NE) + (t >= 3 * NE) + (t >= 4 * NE);
  int e = t - r * NE;
  const int* srcs = r == 0 ? pins_src : r == 1 ? connect_src
                   : r == 2 ? pt_src : r == 3 ? pinned_src : pf_src;
  const int* dsts = r == 0 ? pins_dst : r == 1 ? connect_dst
                   : r == 2 ? pt_dst : r == 3 ? pinned_dst : pf_dst;
  int off = r == 0 ? 0 : r == 1 ? 10000 : r == 2 ? 30000 : r == 3 ? 50000 : 100000;
  int s = srcs[e];
  int g = off + dsts[e];
  int pos = atomicAdd(&cursor[g], 1);
  int cpos = bases[g] + pos;
  if (r < 3) {
    int soff = r == 0 ? 0 : r == 1 ? 50000 : 70000;
    float w = rsqrtf(fmaxf((float)srccnt[soff + s], 1.f));
    csr_gc[cpos] = make_int2(s, __float_as_int(w));
  } else {
    csr_nn[cpos - 300000] = make_int2(e, s);
  }
}

// ---------- K_GC_FIN: gc gather + finalize fused (S never hits memory) ----------
// blocks [0,625):   net rows, 16/block   (gather pins + W_pins/W_net fin)
// blocks [625,3125): gcell rows, 8/block (gather conn & pt halves + fin)
__global__ __launch_bounds__(512) void k_gc_fin(
    const int* __restrict__ hist, const int* __restrict__ bases,
    const int2* __restrict__ csr_gc,
    const float* __restrict__ node_feat, const float* __restrict__ hanna_feat,
    const float* __restrict__ net_feat,
    const float* __restrict__ W_pins, const float* __restrict__ b_pins,
    const float* __restrict__ W_net, const float* __restrict__ b_net,
    const float* __restrict__ W_connect, const float* __restrict__ b_connect,
    const float* __restrict__ W_pt, const float* __restrict__ b_pt,
    float* __restrict__ out) {
  __shared__ float Wa[1024], Wb[1024];
  __shared__ float srow[16][32];
  int b = blockIdx.x, tid = threadIdx.x;
  if (b < 625) {  // ---- net: rows [b*16, b*16+16) ----
    for (int k = tid; k < 1024; k += 512) {
      Wa[k] = W_pins[k];
      Wb[k] = W_net[k];
    }
    int rl = tid >> 5, o = tid & 31;
    int r = b * 16 + rl;
    int base = bases[r], deg = hist[r];
    float acc = 0.f;
    int k = 0;
    for (; k + 1 < deg; k += 2) {
      int2 pa = csr_gc[base + k], pb = csr_gc[base + k + 1];
      acc += node_feat[(size_t)pa.x * 32 + o] * __int_as_float(pa.y) +
             node_feat[(size_t)pb.x * 32 + o] * __int_as_float(pb.y);
    }
    if (k < deg) {
      int2 pa = csr_gc[base + k];
      acc += node_feat[(size_t)pa.x * 32 + o] * __int_as_float(pa.y);
    }
    srow[rl][o] = acc;
    __syncthreads();
    float a1 = 0.f, a2 = 0.f;
#pragma unroll 8
    for (int i = 0; i < 32; i++) {
      a1 += srow[rl][i] * Wa[i * 32 + o];
      a2 += net_feat[(size_t)r * 32 + i] * Wb[i * 32 + o];
    }
    out[1600000 + (size_t)r * 32 + o] =
        a1 * rsqrtf(fmaxf((float)deg, 1.f)) + b_pins[o] + a2 + b_net[o];
    return;
  }
  // ---- gcell: rows [bb*8, bb*8+8), conn half + pt half ----
  int bb = b - 625;
  for (int k = tid; k < 1024; k += 512) {
    Wa[k] = W_connect[k];
    Wb[k] = W_pt[k];
  }
  int rl = tid >> 6;              // 0..7 row-in-block
  int half = (tid >> 5) & 1;      // 0=connect, 1=pt
  int o = tid & 31;
  int r = bb * 8 + rl;
  int g = (half ? 30000 : 10000) + r;
  const float* feat = half ? node_feat : hanna_feat;
  int base = bases[g], deg = hist[g];
  float acc = 0.f;
  int k = 0;
  for (; k + 1 < deg; k += 2) {
    int2 pa = csr_gc[base + k], pb = csr_gc[base + k + 1];
    acc += feat[(size_t)pa.x * 32 + o] * __int_as_float(pa.y) +
           feat[(size_t)pb.x * 32 + o] * __int_as_float(pb.y);
  }
  if (k < deg) {
    int2 pa = csr_gc[base + k];
    acc += feat[(size_t)pa.x * 32 + o] * __int_as_float(pa.y);
  }
  srow[rl * 2 + half][o] = acc;
  __syncthreads();
  if (half == 0) {
    float a1 = 0.f, a2 = 0.f;
#pragma unroll 8
    for (int i = 0; i < 32; i++) {
      a1 += srow[rl * 2 + 0][i] * Wa[i * 32 + o];
      a2 += srow[rl * 2 + 1][i] * Wb[i * 32 + o];
    }
    out[1920000 + (size_t)r * 32 + o] =
        a1 * rsqrtf(fmaxf((float)hist[10000 + r], 1.f)) + b_connect[o] +
        a2 * rsqrtf(fmaxf((float)hist[30000 + r], 1.f)) + b_pt[o];
  }
}

// ---------- K_TAIL: NNConv gather only (cells), writes d_out ----------
__global__ __launch_bounds__(512) void k_tail(
    const int* __restrict__ hist, const int* __restrict__ bases,
    const int2* __restrict__ csr_nn,
    const float* __restrict__ pin_feat, const float* __restrict__ edge_feat,
    const u16* __restrict__ T_net, const u16* __restrict__ T_han,
    const float* __restrict__ C_net, const float* __restrict__ C_han,
    const float* __restrict__ b_pinned, const float* __restrict__ b_pf,
    float* __restrict__ out) {
  int t = blockIdx.x * 512 + threadIdx.x;  // 3125*512 = 1.6M exact
  int d = t >> 5, o = t & 31;
  float a0 = 0.f, a1 = 0.f;
  {  // conv0: 'pinned' net -> cell
    int g = 50000 + d;
    int base = bases[g] - 300000, deg = hist[g];
    int k = 0;
    for (; k + 1 < deg; k += 2) {
      int2 ea = csr_nn[base + k], eb = csr_nn[base + k + 1];
      a0 += nn_msg(ea.x, ea.y, pin_feat, T_net, C_net, o) +
            nn_msg(eb.x, eb.y, pin_feat, T_net, C_net, o);
    }
    if (k < deg) {
      int2 ea = csr_nn[base + k];
      a0 += nn_msg(ea.x, ea.y, pin_feat, T_net, C_net, o);
    }
    a0 /= fmaxf((float)deg, 1.f);
  }
  {  // conv1: 'point-from' gcell -> cell
    int g = 100000 + d;
    int base = bases[g] - 300000, deg = hist[g];
    int k = 0;
    for (; k + 1 < deg; k += 2) {
      int2 ea = csr_nn[base + k], eb = csr_nn[base + k + 1];
      a1 += nn_msg(ea.x, ea.y, edge_feat, T_han, C_han, o) +
            nn_msg(eb.x, eb.y, edge_feat, T_han, C_han, o);
    }
    if (k < deg) {
      int2 ea = csr_nn[base + k];
      a1 += nn_msg(ea.x, ea.y, edge_feat, T_han, C_han, o);
    }
    a1 /= fmaxf((float)deg, 1.f);
  }
  out[(size_t)d * 32 + o] = a0 + a1 + b_pinned[o] + b_pf[o];
}

extern "C" void kernel_launch(void* const* d_in, const int* in_sizes, int n_in,
                              void* d_out, int out_size, void* d_ws, size_t ws_size,
                              hipStream_t stream) {
  const float* node_feat  = (const float*)d_in[0];
  const float* net_feat   = (const float*)d_in[1];
  const float* pin_feat   = (const float*)d_in[2];
  const float* hanna_feat = (const float*)d_in[3];
  const float* edge_feat  = (const float*)d_in[4];
  const int* pins_src    = (const int*)d_in[5];
  const int* pins_dst    = (const int*)d_in[6];
  const int* pinned_src  = (const int*)d_in[7];
  const int* pinned_dst  = (const int*)d_in[8];
  const int* connect_src = (const int*)d_in[9];
  const int* connect_dst = (const int*)d_in[10];
  const int* pt_src      = (const int*)d_in[11];
  const int* pt_dst      = (const int*)d_in[12];
  const int* pf_src      = (const int*)d_in[13];
  const int* pf_dst      = (const int*)d_in[14];
  const float* W_net     = (const float*)d_in[15];
  const float* b_net     = (const float*)d_in[16];
  const float* W_topo    = (const float*)d_in[17];
  const float* b_topo    = (const float*)d_in[18];
  const float* W_pins    = (const float*)d_in[19];
  const float* b_pins    = (const float*)d_in[20];
  const float* W_connect = (const float*)d_in[21];
  const float* b_connect = (const float*)d_in[22];
  const float* W_pt      = (const float*)d_in[23];
  const float* b_pt      = (const float*)d_in[24];
  const float* b_pinned  = (const float*)d_in[25];
  const float* b_pf      = (const float*)d_in[26];
  float* out = (float*)d_out;

  // ---- workspace layout (40.85 MB total; < proven 48.44 MB) ----
  int* wi = (int*)d_ws;
  int* hist    = wi + 0;          // [0, 150016)
  int* cursor  = wi + 150016;     // [150016, 300032)
  int* srccnt  = wi + 300032;     // [300032, 420032)
  int* bases   = wi + 420032;     // [420032, 570064)
  int2* csr_gc = (int2*)(wi + 570192);   // 300,000 * 8B  -> int end 1,170,192
  int2* csr_nn = (int2*)(wi + 1170192);  // 200,000 * 8B  -> int end 1,570,192
  float* wf = (float*)d_ws;
  float* C_net  = wf + 1570192;   // NN*32 -> 1,890,192
  float* C_han  = wf + 1890192;   // NG*32 -> 2,530,192 (byte 10,120,768)
  u16* T_net = (u16*)((char*)d_ws + 10120832);             // NN*512 bf16
  u16* T_han = (u16*)((char*)d_ws + 10120832 + 10240000);  // NG*512 bf16
  // end byte: 40,840,832

  hipMemsetAsync(d_ws, 0, 420032 * sizeof(int), stream);  // hist+cursor+srccnt

  k_front<<<2540, 512, 0, stream>>>(
      net_feat, hanna_feat, W_topo, b_topo, T_net, T_han, C_net, C_han,
      pins_src, pins_dst, pinned_dst, pf_dst, connect_src, connect_dst,
      pt_src, pt_dst, hist, srccnt);

  k_scan<<<NBLK, 256, 0, stream>>>(hist, bases);

  k_fill<<<(5 * NE + 511) / 512, 512, 0, stream>>>(
      pins_src, pins_dst, connect_src, connect_dst, pt_src, pt_dst,
      pinned_src, pinned_dst, pf_src, pf_dst, srccnt, bases, cursor,
      csr_gc, csr_nn);

  k_gc_fin<<<3125, 512, 0, stream>>>(
      hist, bases, csr_gc, node_feat, hanna_feat, net_feat,
      W_pins, b_pins, W_net, b_net, W_connect, b_connect, W_pt, b_pt, out);

  k_tail<<<3125, 512, 0, stream>>>(
      hist, bases, csr_nn, pin_feat, edge_feat,
      T_net, T_han, C_net, C_han, b_pinned, b_pf, out);
}